// Round 12
// baseline (193.561 us; speedup 1.0000x reference)
//
#include <hip/hip_runtime.h>
#include <math.h>

#define B_    4
#define N_    16384
#define S_    1024
#define C1_   128
#define C2_   256
#define CIN_  384
#define H1_   256
#define H2_   128
#define BN_EPS_     1e-5f
#define INTERP_EPS_ 1e-8f

typedef _Float16 f16;
typedef _Float16 f16x4 __attribute__((ext_vector_type(4)));
typedef _Float16 f16x8 __attribute__((ext_vector_type(8)));
typedef float    f32x4 __attribute__((ext_vector_type(4)));
typedef unsigned int u32;

// async global->LDS, 16B per lane; LDS dest = wave-uniform base + lane*16
#define GLD16(g, l) \
  __builtin_amdgcn_global_load_lds((const __attribute__((address_space(1))) void*)(g), \
                                   (__attribute__((address_space(3))) void*)(l), 16, 0, 0)

// ---- ws layout (bytes) ----
#define WS_XI   1048576      // f16 [65536][256] interpolated features
#define WS_W1F  68157440     // f16 [256][384]
#define WS_W2F  68354048     // f16 [128][256]
#define WS_SC1  68419584
#define WS_SH1  68420608
#define WS_SC2  68421632
#define WS_SH2  68422144

// ---------------------------------------------------------------------------
// front: fused {topk, interp, prep}. Blocks 0..1023: 64 points each
// (4 threads/point, 256 candidates each). Blocks >=1024: prep.
// ---------------------------------------------------------------------------
__device__ __forceinline__ u32 umin_(u32 a, u32 b) { return a < b ? a : b; }
__device__ __forceinline__ u32 umax_(u32 a, u32 b) { return a > b ? a : b; }

#define KINS(k) do { \
    u32 c1 = umax_(s0, (k)); s0 = umin_(s0, (k)); \
    u32 c2 = umax_(s1, c1);  s1 = umin_(s1, c1);  \
    u32 c3 = umax_(s2, c2);  s2 = umin_(s2, c2);  \
    u32 c4 = umax_(s3, c3);  s3 = umin_(s3, c3);  \
    s4 = umin_(s4, c4); } while (0)

#define CSWAP(a_, b_) do { \
    if (rd[b_] < rd[a_] || (rd[b_] == rd[a_] && ri[b_] < ri[a_])) { \
      double td = rd[a_]; rd[a_] = rd[b_]; rd[b_] = td; \
      int ti = ri[a_]; ri[a_] = ri[b_]; ri[b_] = ti; } } while (0)

__global__ __launch_bounds__(256) void front_kernel(
    const float* __restrict__ xyz1, const float* __restrict__ xyz2,
    const float* __restrict__ points2,
    const float* __restrict__ w1, const float* __restrict__ w2,
    const float* __restrict__ g1, const float* __restrict__ b1,
    const float* __restrict__ m1, const float* __restrict__ v1,
    const float* __restrict__ g2, const float* __restrict__ b2,
    const float* __restrict__ m2, const float* __restrict__ v2,
    f16* __restrict__ xi, f16* __restrict__ w1f, f16* __restrict__ w2f,
    float* __restrict__ sc1, float* __restrict__ sh1,
    float* __restrict__ sc2, float* __restrict__ sh2)
{
    const int bid = blockIdx.x;
    const int t   = threadIdx.x;

    if (bid >= 1024) {                    // ---- prep blocks ----
        const int tg = (bid - 1024) * 256 + t;
        if (tg < 98304) {
            w1f[tg] = (f16)w1[tg];
        } else if (tg < 131072) {
            w2f[tg - 98304] = (f16)w2[tg - 98304];
        } else if (tg < 131328) {
            const int c = tg - 131072;
            const float s = g1[c] / sqrtf(v1[c] + BN_EPS_);
            sc1[c] = s; sh1[c] = b1[c] - m1[c] * s;
        } else if (tg < 131456) {
            const int c = tg - 131328;
            const float s = g2[c] / sqrtf(v2[c] + BN_EPS_);
            sc2[c] = s; sh2[c] = b2[c] - m2[c] * s;
        }
        return;
    }

    __shared__ float4 q[S_ + 4];          // stagger: idx = s + (s>>8)
    __shared__ int   idr[64][3];
    __shared__ float wtr[64][3];

    const int b     = bid >> 8;           // 256 blocks/batch, 64 pts each
    const int pbase = (bid & 255) << 6;

    for (int i = t; i < S_; i += 256) {
        const float* s = &xyz2[((size_t)b * S_ + i) * 3];
        float4 v; v.x = s[0]; v.y = s[1]; v.z = s[2]; v.w = 0.0f;
        q[i + (i >> 8)] = v;
    }
    __syncthreads();

    {   // ---- topk: 4 threads/point, 256 candidates each ----
        const int p     = pbase + (t >> 2);
        const int chunk = t & 3;
        const int qb    = chunk * 257;    // chunk*256 + chunk stagger
        const int ebase = chunk << 8;
        const float* pp = &xyz1[((size_t)b * N_ + p) * 3];
        const float px = pp[0], py = pp[1], pz = pp[2];

        u32 s0 = 0xFFFFFFFFu, s1 = 0xFFFFFFFFu, s2 = 0xFFFFFFFFu,
            s3 = 0xFFFFFFFFu, s4 = 0xFFFFFFFFu;

        for (int i = 0; i < 256; i += 4) {
            #pragma unroll
            for (int u = 0; u < 4; ++u) {
                const float4 c = q[qb + i + u];
                const float dx = px - c.x, dy = py - c.y, dz = pz - c.z;
                const float dd = fmaf(dx, dx, fmaf(dy, dy, dz * dz));
                const u32 k = (__float_as_uint(dd) & 0xFFFFFC00u) | (u32)(ebase + i + u);
                KINS(k);
            }
        }
        #pragma unroll
        for (int msk = 1; msk <= 2; msk <<= 1) {
            u32 e0 = __shfl_xor(s0, msk), e1 = __shfl_xor(s1, msk);
            u32 e2 = __shfl_xor(s2, msk), e3 = __shfl_xor(s3, msk);
            u32 e4 = __shfl_xor(s4, msk);
            KINS(e0); KINS(e1); KINS(e2); KINS(e3); KINS(e4);
        }
        if (chunk == 0) {
            const double px6 = px, py6 = py, pz6 = pz;
            double rd[5]; int ri[5];
            const u32 ks[5] = {s0, s1, s2, s3, s4};
            #pragma unroll
            for (int j = 0; j < 5; ++j) {
                const int si = (int)(ks[j] & 1023u); ri[j] = si;
                const float4 c = q[si + (si >> 8)];
                const double dx = px6 - (double)c.x, dy = py6 - (double)c.y, dz = pz6 - (double)c.z;
                rd[j] = dx * dx + dy * dy + dz * dz;
            }
            CSWAP(0,1); CSWAP(1,2); CSWAP(0,1); CSWAP(2,3); CSWAP(1,2);
            CSWAP(0,1); CSWAP(3,4); CSWAP(2,3); CSWAP(1,2); CSWAP(0,1);
            const float r0 = 1.0f / ((float)rd[0] + INTERP_EPS_);
            const float r1 = 1.0f / ((float)rd[1] + INTERP_EPS_);
            const float r2 = 1.0f / ((float)rd[2] + INTERP_EPS_);
            const float rs = r0 + r1 + r2;
            const int r = t >> 2;
            idr[r][0] = ri[0]; idr[r][1] = ri[1]; idr[r][2] = ri[2];
            wtr[r][0] = r0 / rs; wtr[r][1] = r1 / rs; wtr[r][2] = r2 / rs;
        }
    }
    __syncthreads();

    // ---- interp: 2 passes of {32 rows x 8 lanes, 32 cols/lane} ----
    #pragma unroll
    for (int rr = 0; rr < 64; rr += 32) {
        const int r = (t >> 3) + rr, j = t & 7;
        const int i0 = idr[r][0], i1 = idr[r][1], i2 = idr[r][2];
        const float w0 = wtr[r][0], w1w = wtr[r][1], w2w = wtr[r][2];
        const float* p2b = points2 + (size_t)b * S_ * C2_;
        const int c0 = j * 32;
        float a[32];
        #pragma unroll
        for (int g = 0; g < 8; ++g) {
            const float4 f = *(const float4*)&p2b[i0 * C2_ + c0 + g * 4];
            a[g*4+0] = w0 * f.x; a[g*4+1] = w0 * f.y; a[g*4+2] = w0 * f.z; a[g*4+3] = w0 * f.w;
        }
        #pragma unroll
        for (int g = 0; g < 8; ++g) {
            const float4 f = *(const float4*)&p2b[i1 * C2_ + c0 + g * 4];
            a[g*4+0] = fmaf(w1w, f.x, a[g*4+0]); a[g*4+1] = fmaf(w1w, f.y, a[g*4+1]);
            a[g*4+2] = fmaf(w1w, f.z, a[g*4+2]); a[g*4+3] = fmaf(w1w, f.w, a[g*4+3]);
        }
        #pragma unroll
        for (int g = 0; g < 8; ++g) {
            const float4 f = *(const float4*)&p2b[i2 * C2_ + c0 + g * 4];
            a[g*4+0] = fmaf(w2w, f.x, a[g*4+0]); a[g*4+1] = fmaf(w2w, f.y, a[g*4+1]);
            a[g*4+2] = fmaf(w2w, f.z, a[g*4+2]); a[g*4+3] = fmaf(w2w, f.w, a[g*4+3]);
        }
        const size_t grow = (size_t)(b * N_ + pbase + r);
        #pragma unroll
        for (int g8 = 0; g8 < 4; ++g8) {
            f16x8 o;
            #pragma unroll
            for (int e = 0; e < 8; ++e) o[e] = (f16)a[g8 * 8 + e];
            *(f16x8*)&xi[grow * C2_ + c0 + g8 * 8] = o;
        }
    }
}

// ---------------------------------------------------------------------------
// mlp: fused {gemm1 -> h in swizzled LDS, gemm2 -> out}. 64-row blocks
// (grid 1024), full 256 h-cols per block -> gemm2 block-local.
// LDS: phase1 As dbuf 8K @0 + Bs dbuf 32K @8K; phase2 Bs2 dbuf 16K @0 +
// Ht 32K @16K; union 48 KB -> 3 blocks/CU.
// ---------------------------------------------------------------------------
__global__ __launch_bounds__(256, 3) void mlp_kernel(
    const float* __restrict__ points1, const f16* __restrict__ xi,
    const f16* __restrict__ w1f, const f16* __restrict__ w2f,
    const float* __restrict__ sc1v, const float* __restrict__ sh1v,
    const float* __restrict__ sc2v, const float* __restrict__ sh2v,
    float* __restrict__ out)
{
    extern __shared__ __align__(16) char smem[];     // 49152 B
    f16* As = (f16*)smem;                            // phase1 dbuf 2x(64x32)
    f16* Bs = (f16*)(smem + 8192);                   // phase1 dbuf 2x(256x32)
    char* Ht = smem + 16384;                         // phase2 h [64][256] swizzled

    const int t = threadIdx.x;
    const int w = t >> 6;
    const int lane = t & 63;
    const int wr = w >> 1, wc = w & 1;
    const int lrow = lane & 15, lhi = lane >> 4;
    const int rowbase = blockIdx.x * 64;

    const int srow = t >> 2, kq = t & 3;             // points1: 4 thr/row, 8 f32 each
    const float* p1r = points1 + (size_t)(rowbase + srow) * C1_;

    f32x4 acc[2][8] = {};
    float4 pre0, pre1;

    // ---- phase 1 prologue: stage kb=0 (points1) into buffer 0 ----
    {
        const float* src = p1r + kq * 8;
        pre0 = *(const float4*)(src + 0);
        pre1 = *(const float4*)(src + 4);
        f16* asrow = As + srow * 32 + kq * 8;
        f16x4 o0 = {(f16)pre0.x, (f16)pre0.y, (f16)pre0.z, (f16)pre0.w};
        f16x4 o1 = {(f16)pre1.x, (f16)pre1.y, (f16)pre1.z, (f16)pre1.w};
        *(f16x4*)(asrow + 0) = o0; *(f16x4*)(asrow + 4) = o1;
        #pragma unroll
        for (int j = 0; j < 4; ++j) {
            const int c = j * 256 + t;
            GLD16(w1f + (size_t)(c >> 2) * CIN_ + (c & 3) * 8,
                  (char*)Bs + (j * 4096 + w * 1024));
        }
    }
    __syncthreads();

    for (int step = 0; step < 12; ++step) {
        const int pb = step & 1, nb = pb ^ 1;
        const int nkb = (step + 1) * 32;
        const bool has_next = (step < 11);
        const bool nextA = (nkb < C1_);

        if (has_next) {
            if (nextA) {
                const float* src = p1r + nkb + kq * 8;
                pre0 = *(const float4*)(src + 0);
                pre1 = *(const float4*)(src + 4);
            } else {
                const int kk = nkb - C1_;
                GLD16(xi + (size_t)(rowbase + (t >> 2)) * C2_ + kk + (t & 3) * 8,
                      (char*)As + (nb * 4096 + w * 1024));
            }
            #pragma unroll
            for (int j = 0; j < 4; ++j) {
                const int c = j * 256 + t;
                GLD16(w1f + (size_t)(c >> 2) * CIN_ + nkb + (c & 3) * 8,
                      (char*)Bs + (nb * 16384 + j * 4096 + w * 1024));
            }
        }

        {   // MFMA on current buffers: 64 rows x 256 cols, acc[2][8]
            const f16* Ac = As + pb * 2048;
            const f16* Bc = Bs + pb * 8192;
            f16x8 af[2], bf[8];
            #pragma unroll
            for (int m = 0; m < 2; ++m)
                af[m] = *(const f16x8*)&Ac[(wr * 32 + m * 16 + lrow) * 32 + lhi * 8];
            #pragma unroll
            for (int n = 0; n < 8; ++n)
                bf[n] = *(const f16x8*)&Bc[(wc * 128 + n * 16 + lrow) * 32 + lhi * 8];
            #pragma unroll
            for (int m = 0; m < 2; ++m)
                #pragma unroll
                for (int n = 0; n < 8; ++n)
                    acc[m][n] = __builtin_amdgcn_mfma_f32_16x16x32_f16(af[m], bf[n], acc[m][n], 0, 0, 0);
        }

        if (has_next && nextA) {
            f16* asrow = As + nb * 2048 + srow * 32 + kq * 8;
            f16x4 o0 = {(f16)pre0.x, (f16)pre0.y, (f16)pre0.z, (f16)pre0.w};
            f16x4 o1 = {(f16)pre1.x, (f16)pre1.y, (f16)pre1.z, (f16)pre1.w};
            *(f16x4*)(asrow + 0) = o0; *(f16x4*)(asrow + 4) = o1;
        }
        __syncthreads();
    }
    // phase-1 LDS dead from here.

    // ---- transition: issue phase-2 prologue staging, then h -> LDS ----
    #pragma unroll
    for (int j = 0; j < 2; ++j) {                    // w2f kb=0 -> Bs2 buf0 @smem[0,8K)
        const int c = j * 256 + t;
        GLD16(w2f + (size_t)(c >> 2) * H1_ + (c & 3) * 8,
              smem + (j * 4096 + w * 1024));
    }
    // BN+ReLU epilogue of phase 1 -> swizzled Ht [64][256]
    #pragma unroll
    for (int n = 0; n < 8; ++n) {
        const int col = wc * 128 + n * 16 + lrow;
        const float sc = sc1v[col], sh = sh1v[col];
        #pragma unroll
        for (int m = 0; m < 2; ++m) {
            #pragma unroll
            for (int i = 0; i < 4; ++i) {
                const int row = wr * 32 + m * 16 + lhi * 4 + i;
                const float v = fmaxf(fmaf(acc[m][n][i], sc, sh), 0.0f);
                const u32 byteoff = (u32)(row * 512 + col * 2) ^ ((u32)(row & 7) << 4);
                *(f16*)(Ht + byteoff) = (f16)v;
            }
        }
    }
    __syncthreads();

    // ---- phase 2: out = relu(bn(h @ w2^T)), 8 K-steps, dbuf w2 staging ----
    f32x4 acc2[2][4] = {};
    for (int step = 0; step < 8; ++step) {
        const int pb = step & 1, nb = pb ^ 1;
        const int nkb = (step + 1) * 32;
        if (step < 7) {
            #pragma unroll
            for (int j = 0; j < 2; ++j) {
                const int c = j * 256 + t;
                GLD16(w2f + (size_t)(c >> 2) * H1_ + nkb + (c & 3) * 8,
                      smem + (nb * 8192 + j * 4096 + w * 1024));
            }
        }
        f16x8 af[2], bf[4];
        #pragma unroll
        for (int m = 0; m < 2; ++m) {
            const int row = wr * 32 + m * 16 + lrow;
            const u32 byteoff = (u32)(row * 512 + (step * 32 + lhi * 8) * 2) ^ ((u32)(row & 7) << 4);
            af[m] = *(const f16x8*)(Ht + byteoff);
        }
        const f16* Bc = (const f16*)(smem + pb * 8192);
        #pragma unroll
        for (int n = 0; n < 4; ++n)
            bf[n] = *(const f16x8*)&Bc[(wc * 64 + n * 16 + lrow) * 32 + lhi * 8];
        #pragma unroll
        for (int m = 0; m < 2; ++m)
            #pragma unroll
            for (int n = 0; n < 4; ++n)
                acc2[m][n] = __builtin_amdgcn_mfma_f32_16x16x32_f16(af[m], bf[n], acc2[m][n], 0, 0, 0);
        __syncthreads();
    }

    // ---- epilogue: out f32 ----
    #pragma unroll
    for (int n = 0; n < 4; ++n) {
        const int col = wc * 64 + n * 16 + lrow;
        const float sc = sc2v[col], sh = sh2v[col];
        #pragma unroll
        for (int m = 0; m < 2; ++m) {
            const int row0 = rowbase + wr * 32 + m * 16 + lhi * 4;
            #pragma unroll
            for (int i = 0; i < 4; ++i) {
                out[(size_t)(row0 + i) * H2_ + col] = fmaxf(fmaf(acc2[m][n][i], sc, sh), 0.0f);
            }
        }
    }
}

// ---------------------------------------------------------------------------
extern "C" void kernel_launch(void* const* d_in, const int* in_sizes, int n_in,
                              void* d_out, int out_size, void* d_ws, size_t ws_size,
                              hipStream_t stream) {
    const float* xyz1    = (const float*)d_in[0];
    const float* xyz2    = (const float*)d_in[1];
    const float* points1 = (const float*)d_in[2];
    const float* points2 = (const float*)d_in[3];
    const float* w1      = (const float*)d_in[4];
    const float* g1      = (const float*)d_in[5];
    const float* b1      = (const float*)d_in[6];
    const float* m1      = (const float*)d_in[7];
    const float* v1      = (const float*)d_in[8];
    const float* w2      = (const float*)d_in[9];
    const float* g2      = (const float*)d_in[10];
    const float* b2      = (const float*)d_in[11];
    const float* m2      = (const float*)d_in[12];
    const float* v2      = (const float*)d_in[13];
    float* out = (float*)d_out;

    char* ws = (char*)d_ws;
    f16*   xi_ws = (f16*)(ws + WS_XI);
    f16*   w1f   = (f16*)(ws + WS_W1F);
    f16*   w2f   = (f16*)(ws + WS_W2F);
    float* sc1   = (float*)(ws + WS_SC1);
    float* sh1   = (float*)(ws + WS_SH1);
    float* sc2   = (float*)(ws + WS_SC2);
    float* sh2   = (float*)(ws + WS_SH2);

    front_kernel<<<dim3(1538), dim3(256), 0, stream>>>(
        xyz1, xyz2, points2, w1, w2, g1, b1, m1, v1, g2, b2, m2, v2,
        xi_ws, w1f, w2f, sc1, sh1, sc2, sh2);
    mlp_kernel<<<dim3(1024), dim3(256), 49152, stream>>>(
        points1, xi_ws, w1f, w2f, sc1, sh1, sc2, sh2, out);
}

// Round 13
// 184.137 us; speedup vs baseline: 1.0512x; 1.0512x over previous
//
#include <hip/hip_runtime.h>
#include <math.h>

#define B_    4
#define N_    16384
#define S_    1024
#define C1_   128
#define C2_   256
#define CIN_  384
#define H1_   256
#define H2_   128
#define BN_EPS_     1e-5f
#define INTERP_EPS_ 1e-8f

typedef _Float16 f16;
typedef _Float16 f16x4 __attribute__((ext_vector_type(4)));
typedef _Float16 f16x8 __attribute__((ext_vector_type(8)));
typedef float    f32x4 __attribute__((ext_vector_type(4)));
typedef unsigned int u32;

// async global->LDS, 16B per lane; LDS dest = wave-uniform base + lane*16
#define GLD16(g, l) \
  __builtin_amdgcn_global_load_lds((const __attribute__((address_space(1))) void*)(g), \
                                   (__attribute__((address_space(3))) void*)(l), 16, 0, 0)

// ---- ws layout (bytes) ----
#define WS_XI   1048576      // f16 [65536][256] interpolated features
#define WS_W1F  68157440     // f16 [256][384]
#define WS_W2F  68354048     // f16 [128][256]
#define WS_SC1  68419584
#define WS_SH1  68420608
#define WS_SC2  68421632
#define WS_SH2  68422144

// ---------------------------------------------------------------------------
// front: fused {topk, interp, prep}. Blocks 0..2047: 32 points each
// (8 threads/point, 128 candidates each). Blocks >=2048: prep.
// topk scan uses 4 INDEPENDENT top-5 chains per thread (ILP fix for the
// serial min/max dependency chain diagnosed in r11: VALUBusy 52%).
// Keys unique (idx in low bits) -> top-5 set is order-independent.
// ---------------------------------------------------------------------------
__device__ __forceinline__ u32 umin_(u32 a, u32 b) { return a < b ? a : b; }
__device__ __forceinline__ u32 umax_(u32 a, u32 b) { return a > b ? a : b; }

#define KINS5(S0,S1,S2,S3,S4,k) do { \
    u32 c1 = umax_(S0, (k)); S0 = umin_(S0, (k)); \
    u32 c2 = umax_(S1, c1);  S1 = umin_(S1, c1);  \
    u32 c3 = umax_(S2, c2);  S2 = umin_(S2, c2);  \
    u32 c4 = umax_(S3, c3);  S3 = umin_(S3, c3);  \
    S4 = umin_(S4, c4); } while (0)

#define CSWAP(a_, b_) do { \
    if (rd[b_] < rd[a_] || (rd[b_] == rd[a_] && ri[b_] < ri[a_])) { \
      double td = rd[a_]; rd[a_] = rd[b_]; rd[b_] = td; \
      int ti = ri[a_]; ri[a_] = ri[b_]; ri[b_] = ti; } } while (0)

__global__ __launch_bounds__(256) void front_kernel(
    const float* __restrict__ xyz1, const float* __restrict__ xyz2,
    const float* __restrict__ points2,
    const float* __restrict__ w1, const float* __restrict__ w2,
    const float* __restrict__ g1, const float* __restrict__ b1,
    const float* __restrict__ m1, const float* __restrict__ v1,
    const float* __restrict__ g2, const float* __restrict__ b2,
    const float* __restrict__ m2, const float* __restrict__ v2,
    f16* __restrict__ xi, f16* __restrict__ w1f, f16* __restrict__ w2f,
    float* __restrict__ sc1, float* __restrict__ sh1,
    float* __restrict__ sc2, float* __restrict__ sh2)
{
    const int bid = blockIdx.x;
    const int t   = threadIdx.x;

    if (bid >= 2048) {                    // ---- prep blocks ----
        const int tg = (bid - 2048) * 256 + t;
        if (tg < 98304) {
            w1f[tg] = (f16)w1[tg];
        } else if (tg < 131072) {
            w2f[tg - 98304] = (f16)w2[tg - 98304];
        } else if (tg < 131328) {
            const int c = tg - 131072;
            const float s = g1[c] / sqrtf(v1[c] + BN_EPS_);
            sc1[c] = s; sh1[c] = b1[c] - m1[c] * s;
        } else if (tg < 131456) {
            const int c = tg - 131328;
            const float s = g2[c] / sqrtf(v2[c] + BN_EPS_);
            sc2[c] = s; sh2[c] = b2[c] - m2[c] * s;
        }
        return;
    }

    __shared__ float4 q[S_ + 8];
    __shared__ int   idr[32][3];
    __shared__ float wtr[32][3];

    const int b     = bid >> 9;
    const int pbase = (bid & 511) << 5;

    for (int i = t; i < S_; i += 256) {
        const float* s = &xyz2[((size_t)b * S_ + i) * 3];
        float4 v; v.x = s[0]; v.y = s[1]; v.z = s[2]; v.w = 0.0f;
        q[i + (i >> 7)] = v;
    }
    __syncthreads();

    {   // ---- topk: 8 threads/point, 128 candidates each ----
        const int p     = pbase + (t >> 3);
        const int chunk = t & 7;
        const int qb    = chunk * 129;
        const int ebase = chunk << 7;
        const float* pp = &xyz1[((size_t)b * N_ + p) * 3];
        const float px = pp[0], py = pp[1], pz = pp[2];

        const u32 FULL = 0xFFFFFFFFu;
        u32 A0=FULL,A1=FULL,A2=FULL,A3=FULL,A4=FULL;
        u32 B0=FULL,B1=FULL,B2=FULL,B3=FULL,B4=FULL;
        u32 C0=FULL,C1x=FULL,C2x=FULL,C3x=FULL,C4x=FULL;
        u32 D0=FULL,D1=FULL,D2=FULL,D3=FULL,D4=FULL;

        for (int i = 0; i < 128; i += 4) {
            float dd[4];
            #pragma unroll
            for (int u = 0; u < 4; ++u) {
                const float4 c = q[qb + i + u];
                const float dx = px - c.x, dy = py - c.y, dz = pz - c.z;
                dd[u] = fmaf(dx, dx, fmaf(dy, dy, dz * dz));
            }
            const u32 k0 = (__float_as_uint(dd[0]) & 0xFFFFFC00u) | (u32)(ebase + i + 0);
            const u32 k1 = (__float_as_uint(dd[1]) & 0xFFFFFC00u) | (u32)(ebase + i + 1);
            const u32 k2 = (__float_as_uint(dd[2]) & 0xFFFFFC00u) | (u32)(ebase + i + 2);
            const u32 k3 = (__float_as_uint(dd[3]) & 0xFFFFFC00u) | (u32)(ebase + i + 3);
            KINS5(A0,A1,A2,A3,A4,k0);
            KINS5(B0,B1,B2,B3,B4,k1);
            KINS5(C0,C1x,C2x,C3x,C4x,k2);
            KINS5(D0,D1,D2,D3,D4,k3);
        }
        // merge chains: B->A, D->C, C->A (keys unique -> order-independent)
        KINS5(A0,A1,A2,A3,A4,B0); KINS5(A0,A1,A2,A3,A4,B1); KINS5(A0,A1,A2,A3,A4,B2);
        KINS5(A0,A1,A2,A3,A4,B3); KINS5(A0,A1,A2,A3,A4,B4);
        KINS5(C0,C1x,C2x,C3x,C4x,D0); KINS5(C0,C1x,C2x,C3x,C4x,D1); KINS5(C0,C1x,C2x,C3x,C4x,D2);
        KINS5(C0,C1x,C2x,C3x,C4x,D3); KINS5(C0,C1x,C2x,C3x,C4x,D4);
        KINS5(A0,A1,A2,A3,A4,C0); KINS5(A0,A1,A2,A3,A4,C1x); KINS5(A0,A1,A2,A3,A4,C2x);
        KINS5(A0,A1,A2,A3,A4,C3x); KINS5(A0,A1,A2,A3,A4,C4x);

        // merge the 8 chunks (lane bits 0..2): snapshot-then-insert
        #pragma unroll
        for (int msk = 1; msk <= 4; msk <<= 1) {
            u32 e0 = __shfl_xor(A0, msk), e1 = __shfl_xor(A1, msk);
            u32 e2 = __shfl_xor(A2, msk), e3 = __shfl_xor(A3, msk);
            u32 e4 = __shfl_xor(A4, msk);
            KINS5(A0,A1,A2,A3,A4,e0); KINS5(A0,A1,A2,A3,A4,e1); KINS5(A0,A1,A2,A3,A4,e2);
            KINS5(A0,A1,A2,A3,A4,e3); KINS5(A0,A1,A2,A3,A4,e4);
        }

        if (chunk == 0) {
            const double px6 = px, py6 = py, pz6 = pz;
            double rd[5]; int ri[5];
            const u32 ks[5] = {A0, A1, A2, A3, A4};
            #pragma unroll
            for (int j = 0; j < 5; ++j) {
                const int si = (int)(ks[j] & 1023u); ri[j] = si;
                const float4 c = q[si + (si >> 7)];
                const double dx = px6 - (double)c.x, dy = py6 - (double)c.y, dz = pz6 - (double)c.z;
                rd[j] = dx * dx + dy * dy + dz * dz;
            }
            CSWAP(0,1); CSWAP(1,2); CSWAP(0,1); CSWAP(2,3); CSWAP(1,2);
            CSWAP(0,1); CSWAP(3,4); CSWAP(2,3); CSWAP(1,2); CSWAP(0,1);
            const float r0 = 1.0f / ((float)rd[0] + INTERP_EPS_);
            const float r1 = 1.0f / ((float)rd[1] + INTERP_EPS_);
            const float r2 = 1.0f / ((float)rd[2] + INTERP_EPS_);
            const float rs = r0 + r1 + r2;
            const int r = t >> 3;
            idr[r][0] = ri[0]; idr[r][1] = ri[1]; idr[r][2] = ri[2];
            wtr[r][0] = r0 / rs; wtr[r][1] = r1 / rs; wtr[r][2] = r2 / rs;
        }
    }
    __syncthreads();

    {   // ---- interp: 32 rows x 8 lanes, 32 cols/lane ----
        const int r = t >> 3, j = t & 7;
        const int i0 = idr[r][0], i1 = idr[r][1], i2 = idr[r][2];
        const float w0 = wtr[r][0], w1w = wtr[r][1], w2w = wtr[r][2];
        const float* p2b = points2 + (size_t)b * S_ * C2_;
        const int c0 = j * 32;
        float a[32];
        #pragma unroll
        for (int g = 0; g < 8; ++g) {
            const float4 f = *(const float4*)&p2b[i0 * C2_ + c0 + g * 4];
            a[g*4+0] = w0 * f.x; a[g*4+1] = w0 * f.y; a[g*4+2] = w0 * f.z; a[g*4+3] = w0 * f.w;
        }
        #pragma unroll
        for (int g = 0; g < 8; ++g) {
            const float4 f = *(const float4*)&p2b[i1 * C2_ + c0 + g * 4];
            a[g*4+0] = fmaf(w1w, f.x, a[g*4+0]); a[g*4+1] = fmaf(w1w, f.y, a[g*4+1]);
            a[g*4+2] = fmaf(w1w, f.z, a[g*4+2]); a[g*4+3] = fmaf(w1w, f.w, a[g*4+3]);
        }
        #pragma unroll
        for (int g = 0; g < 8; ++g) {
            const float4 f = *(const float4*)&p2b[i2 * C2_ + c0 + g * 4];
            a[g*4+0] = fmaf(w2w, f.x, a[g*4+0]); a[g*4+1] = fmaf(w2w, f.y, a[g*4+1]);
            a[g*4+2] = fmaf(w2w, f.z, a[g*4+2]); a[g*4+3] = fmaf(w2w, f.w, a[g*4+3]);
        }
        const size_t grow = (size_t)(b * N_ + pbase + r);
        #pragma unroll
        for (int g8 = 0; g8 < 4; ++g8) {
            f16x8 o;
            #pragma unroll
            for (int e = 0; e < 8; ++e) o[e] = (f16)a[g8 * 8 + e];
            *(f16x8*)&xi[grow * C2_ + c0 + g8 * 8] = o;
        }
    }
}

// ---------------------------------------------------------------------------
// mlp (round-11 exact): fused {gemm1 -> h in swizzled LDS, gemm2 -> out}.
// 128-row block, full 256 h-cols per block -> gemm2 block-local.
// LDS: phase1 As(16K dbuf)+Bs(32K dbuf); phase2 Bs2(16K dbuf)+Ht(64K); 80 KB.
// ---------------------------------------------------------------------------
__device__ __forceinline__ void mfma_step1(const f16* As, const f16* Bs,
                                           f32x4 (&acc)[4][8],
                                           int wr, int wc, int lrow, int lhi)
{
    f16x8 af[4], bf[8];
    #pragma unroll
    for (int m = 0; m < 4; ++m)
        af[m] = *(const f16x8*)&As[(wr * 64 + m * 16 + lrow) * 32 + lhi * 8];
    #pragma unroll
    for (int n = 0; n < 8; ++n)
        bf[n] = *(const f16x8*)&Bs[(wc * 128 + n * 16 + lrow) * 32 + lhi * 8];
    #pragma unroll
    for (int m = 0; m < 4; ++m)
        #pragma unroll
        for (int n = 0; n < 8; ++n)
            acc[m][n] = __builtin_amdgcn_mfma_f32_16x16x32_f16(af[m], bf[n], acc[m][n], 0, 0, 0);
}

__global__ __launch_bounds__(256, 2) void mlp_kernel(
    const float* __restrict__ points1, const f16* __restrict__ xi,
    const f16* __restrict__ w1f, const f16* __restrict__ w2f,
    const float* __restrict__ sc1v, const float* __restrict__ sh1v,
    const float* __restrict__ sc2v, const float* __restrict__ sh2v,
    float* __restrict__ out)
{
    extern __shared__ __align__(16) char smem[];     // 81920 B
    f16* As = (f16*)smem;                            // phase1 dbuf 2x(128x32)
    f16* Bs = (f16*)(smem + 16384);                  // phase1 dbuf 2x(256x32)
    char* Ht = smem + 16384;                         // phase2 h [128][256] swizzled

    const int t = threadIdx.x;
    const int w = t >> 6;
    const int lane = t & 63;
    const int wr = w >> 1, wc = w & 1;
    const int lrow = lane & 15, lhi = lane >> 4;
    const int rowbase = blockIdx.x * 128;

    const int srow = t >> 1, khalf = t & 1;
    const float* p1r = points1 + (size_t)(rowbase + srow) * C1_;

    f32x4 acc[4][8] = {};
    float4 pre0, pre1, pre2, pre3;

    // ---- phase 1 prologue ----
    {
        const float* src = p1r + khalf * 16;
        pre0 = *(const float4*)(src + 0);
        pre1 = *(const float4*)(src + 4);
        pre2 = *(const float4*)(src + 8);
        pre3 = *(const float4*)(src + 12);
        f16* asrow = As + srow * 32 + khalf * 16;
        f16x4 o0 = {(f16)pre0.x, (f16)pre0.y, (f16)pre0.z, (f16)pre0.w};
        f16x4 o1 = {(f16)pre1.x, (f16)pre1.y, (f16)pre1.z, (f16)pre1.w};
        f16x4 o2 = {(f16)pre2.x, (f16)pre2.y, (f16)pre2.z, (f16)pre2.w};
        f16x4 o3 = {(f16)pre3.x, (f16)pre3.y, (f16)pre3.z, (f16)pre3.w};
        *(f16x4*)(asrow + 0) = o0; *(f16x4*)(asrow + 4) = o1;
        *(f16x4*)(asrow + 8) = o2; *(f16x4*)(asrow + 12) = o3;
        #pragma unroll
        for (int j = 0; j < 4; ++j) {
            const int c = j * 256 + t;
            GLD16(w1f + (size_t)(c >> 2) * CIN_ + (c & 3) * 8,
                  (char*)Bs + (j * 4096 + w * 1024));
        }
    }
    __syncthreads();

    for (int step = 0; step < 12; ++step) {
        const int pb = step & 1, nb = pb ^ 1;
        const int nkb = (step + 1) * 32;
        const bool has_next = (step < 11);
        const bool nextA = (nkb < C1_);

        if (has_next) {
            if (nextA) {
                const float* src = p1r + nkb + khalf * 16;
                pre0 = *(const float4*)(src + 0);
                pre1 = *(const float4*)(src + 4);
                pre2 = *(const float4*)(src + 8);
                pre3 = *(const float4*)(src + 12);
            } else {
                const int kk = nkb - C1_;
                #pragma unroll
                for (int j = 0; j < 2; ++j) {
                    const int c = j * 256 + t;
                    GLD16(xi + (size_t)(rowbase + (c >> 2)) * C2_ + kk + (c & 3) * 8,
                          (char*)As + (nb * 8192 + j * 4096 + w * 1024));
                }
            }
            #pragma unroll
            for (int j = 0; j < 4; ++j) {
                const int c = j * 256 + t;
                GLD16(w1f + (size_t)(c >> 2) * CIN_ + nkb + (c & 3) * 8,
                      (char*)Bs + (nb * 16384 + j * 4096 + w * 1024));
            }
        }

        mfma_step1(As + pb * 4096, Bs + pb * 8192, acc, wr, wc, lrow, lhi);

        if (has_next && nextA) {
            f16* asrow = As + nb * 4096 + srow * 32 + khalf * 16;
            f16x4 o0 = {(f16)pre0.x, (f16)pre0.y, (f16)pre0.z, (f16)pre0.w};
            f16x4 o1 = {(f16)pre1.x, (f16)pre1.y, (f16)pre1.z, (f16)pre1.w};
            f16x4 o2 = {(f16)pre2.x, (f16)pre2.y, (f16)pre2.z, (f16)pre2.w};
            f16x4 o3 = {(f16)pre3.x, (f16)pre3.y, (f16)pre3.z, (f16)pre3.w};
            *(f16x4*)(asrow + 0) = o0; *(f16x4*)(asrow + 4) = o1;
            *(f16x4*)(asrow + 8) = o2; *(f16x4*)(asrow + 12) = o3;
        }
        __syncthreads();
    }

    // ---- transition: phase-2 prologue staging + h -> swizzled LDS ----
    #pragma unroll
    for (int j = 0; j < 2; ++j) {
        const int c = j * 256 + t;
        GLD16(w2f + (size_t)(c >> 2) * H1_ + (c & 3) * 8,
              smem + (j * 4096 + w * 1024));
    }
    #pragma unroll
    for (int n = 0; n < 8; ++n) {
        const int col = wc * 128 + n * 16 + lrow;
        const float sc = sc1v[col], sh = sh1v[col];
        #pragma unroll
        for (int m = 0; m < 4; ++m) {
            #pragma unroll
            for (int i = 0; i < 4; ++i) {
                const int row = wr * 64 + m * 16 + lhi * 4 + i;
                const float v = fmaxf(fmaf(acc[m][n][i], sc, sh), 0.0f);
                const u32 byteoff = (u32)(row * 512 + col * 2) ^ ((u32)(row & 7) << 4);
                *(f16*)(Ht + byteoff) = (f16)v;
            }
        }
    }
    __syncthreads();

    // ---- phase 2 ----
    f32x4 acc2[4][4] = {};
    for (int step = 0; step < 8; ++step) {
        const int pb = step & 1, nb = pb ^ 1;
        const int nkb = (step + 1) * 32;
        if (step < 7) {
            #pragma unroll
            for (int j = 0; j < 2; ++j) {
                const int c = j * 256 + t;
                GLD16(w2f + (size_t)(c >> 2) * H1_ + nkb + (c & 3) * 8,
                      smem + (nb * 8192 + j * 4096 + w * 1024));
            }
        }
        f16x8 af[4], bf[4];
        #pragma unroll
        for (int m = 0; m < 4; ++m) {
            const int row = wr * 64 + m * 16 + lrow;
            const u32 byteoff = (u32)(row * 512 + (step * 32 + lhi * 8) * 2) ^ ((u32)(row & 7) << 4);
            af[m] = *(const f16x8*)(Ht + byteoff);
        }
        const f16* Bc = (const f16*)(smem + pb * 8192);
        #pragma unroll
        for (int n = 0; n < 4; ++n)
            bf[n] = *(const f16x8*)&Bc[(wc * 64 + n * 16 + lrow) * 32 + lhi * 8];
        #pragma unroll
        for (int m = 0; m < 4; ++m)
            #pragma unroll
            for (int n = 0; n < 4; ++n)
                acc2[m][n] = __builtin_amdgcn_mfma_f32_16x16x32_f16(af[m], bf[n], acc2[m][n], 0, 0, 0);
        __syncthreads();
    }

    // ---- epilogue ----
    #pragma unroll
    for (int n = 0; n < 4; ++n) {
        const int col = wc * 64 + n * 16 + lrow;
        const float sc = sc2v[col], sh = sh2v[col];
        #pragma unroll
        for (int m = 0; m < 4; ++m) {
            const int row0 = rowbase + wr * 64 + m * 16 + lhi * 4;
            #pragma unroll
            for (int i = 0; i < 4; ++i) {
                out[(size_t)(row0 + i) * H2_ + col] = fmaxf(fmaf(acc2[m][n][i], sc, sh), 0.0f);
            }
        }
    }
}

// ---------------------------------------------------------------------------
extern "C" void kernel_launch(void* const* d_in, const int* in_sizes, int n_in,
                              void* d_out, int out_size, void* d_ws, size_t ws_size,
                              hipStream_t stream) {
    const float* xyz1    = (const float*)d_in[0];
    const float* xyz2    = (const float*)d_in[1];
    const float* points1 = (const float*)d_in[2];
    const float* points2 = (const float*)d_in[3];
    const float* w1      = (const float*)d_in[4];
    const float* g1      = (const float*)d_in[5];
    const float* b1      = (const float*)d_in[6];
    const float* m1      = (const float*)d_in[7];
    const float* v1      = (const float*)d_in[8];
    const float* w2      = (const float*)d_in[9];
    const float* g2      = (const float*)d_in[10];
    const float* b2      = (const float*)d_in[11];
    const float* m2      = (const float*)d_in[12];
    const float* v2      = (const float*)d_in[13];
    float* out = (float*)d_out;

    char* ws = (char*)d_ws;
    f16*   xi_ws = (f16*)(ws + WS_XI);
    f16*   w1f   = (f16*)(ws + WS_W1F);
    f16*   w2f   = (f16*)(ws + WS_W2F);
    float* sc1   = (float*)(ws + WS_SC1);
    float* sh1   = (float*)(ws + WS_SH1);
    float* sc2   = (float*)(ws + WS_SC2);
    float* sh2   = (float*)(ws + WS_SH2);

    front_kernel<<<dim3(2562), dim3(256), 0, stream>>>(
        xyz1, xyz2, points2, w1, w2, g1, b1, m1, v1, g2, b2, m2, v2,
        xi_ws, w1f, w2f, sc1, sh1, sc2, sh2);
    mlp_kernel<<<dim3(512), dim3(256), 81920, stream>>>(
        points1, xi_ws, w1f, w2f, sc1, sh1, sc2, sh2, out);
}